// Round 5
// baseline (294.200 us; speedup 1.0000x reference)
//
#include <hip/hip_runtime.h>
#include <cstdint>

#define BB 2
#define SS 2048
#define DD 2048
#define HH 16
#define HDIM 128
#define MM (BB * SS)  // 4096

typedef __attribute__((ext_vector_type(8))) short bf16x8;
typedef __attribute__((ext_vector_type(4))) short bf16x4;
typedef __attribute__((ext_vector_type(4))) float f32x4;
typedef __attribute__((ext_vector_type(16))) float f32x16;

__device__ inline short f2bf(float f) {
  union { float f; unsigned u; } v; v.f = f;
  unsigned r = v.u + 0x7FFFu + ((v.u >> 16) & 1u);
  return (short)(r >> 16);
}
__device__ inline float bf2f(short s) {
  union { float f; unsigned u; } v;
  v.u = ((unsigned)(unsigned short)s) << 16;
  return v.f;
}
__device__ inline float asf(int u) { union { int i; float f; } v; v.i = u; return v.f; }
__device__ inline int asi(float f) { union { float f; int i; } v; v.f = f; return v.i; }

__device__ inline unsigned cvtpk_bf16(float lo, float hi) {
  unsigned r;
  asm("v_cvt_pk_bf16_f32 %0, %1, %2" : "=v"(r) : "v"(lo), "v"(hi));
  return r;
}

__device__ inline void gll16(const void* g, void* l) {
  __builtin_amdgcn_global_load_lds(
      (const __attribute__((address_space(1))) void*)g,
      (__attribute__((address_space(3))) void*)l, 16, 0, 0);
}

// ---------------- cast fp32 -> bf16 ----------------
__global__ __launch_bounds__(256) void cast_bf16_kernel(
    const float* __restrict__ x, short* __restrict__ y, int n4) {
  int i = blockIdx.x * 256 + threadIdx.x;
  if (i >= n4) return;
  float4 v = reinterpret_cast<const float4*>(x)[i];
  bf16x4 o;
  o[0] = f2bf(v.x); o[1] = f2bf(v.y); o[2] = f2bf(v.z); o[3] = f2bf(v.w);
  reinterpret_cast<bf16x4*>(y)[i] = o;
}

// ---------------- transpose+cast weight (K,N)fp32 -> (N,K)bf16 ----------------
__global__ __launch_bounds__(256) void transpose_cast_kernel(
    const float* __restrict__ W, short* __restrict__ Wt) {
  __shared__ short tile[64][65];
  int c = threadIdx.x & 63, r4 = threadIdx.x >> 6;
  int n0 = blockIdx.x << 6, k0 = blockIdx.y << 6;
#pragma unroll
  for (int p = 0; p < 16; ++p) {
    int r = (p << 2) + r4;
    tile[c][r] = f2bf(W[(size_t)(k0 + r) * DD + n0 + c]);
  }
  __syncthreads();
#pragma unroll
  for (int p = 0; p < 16; ++p) {
    int r = (p << 2) + r4;
    Wt[(size_t)(n0 + r) * DD + k0 + c] = tile[r][c];
  }
}

// ---------------- transpose V (B,S,D) bf16 head-slices -> Vt (B*H, 128, S) ----------------
__global__ __launch_bounds__(256) void transpose_v_kernel(
    const short* __restrict__ V, short* __restrict__ Vt) {
  __shared__ short tile[64][65];
  int c = threadIdx.x & 63, r4 = threadIdx.x >> 6;
  int s0 = blockIdx.x << 6, d0 = blockIdx.y << 6;
  int bh = blockIdx.z;
  int b = bh >> 4, h = bh & 15;
#pragma unroll
  for (int p = 0; p < 16; ++p) {
    int r = (p << 2) + r4;  // s-local
    tile[c][r] = V[(size_t)(b * SS + s0 + r) * DD + h * HDIM + d0 + c];
  }
  __syncthreads();
#pragma unroll
  for (int p = 0; p < 16; ++p) {
    int r = (p << 2) + r4;  // d-local
    Vt[((size_t)bh * HDIM + d0 + r) * SS + s0 + c] = tile[r][c];
  }
}

// ---------------- fused QKV GEMM, 256x256 8-phase schedule ----------------
// C(4096,6144) = xb(4096,2048) * WqkvT(6144,2048)^T. 512 threads = 8 waves (2Mx4N).
// Per K-tile (BK=64): 4 phases, each {12 ds_read (one quadrant) || gll-stage next
// tile -> other buffer; s_barrier; setprio(1); 16 MFMA; setprio(0); s_barrier},
// then one vmcnt(0)+barrier per tile. Epilogue: Q/K RoPE (Q pre-scaled by
// log2e/sqrt(128)), V plain store.
__global__ __launch_bounds__(512) void qkv_gemm8_kernel(
    const short* __restrict__ A, const short* __restrict__ Bt,
    short* __restrict__ Qb, short* __restrict__ Kb, short* __restrict__ Vb,
    const float* __restrict__ fc, const float* __restrict__ fs) {
  __shared__ short smem[2][32768];  // [buf][ A(16384) | B(16384) ]  = 128 KB
  const int tid = threadIdx.x;
  const int lane = tid & 63, w = tid >> 6;
  const int cl = lane & 15, gq = lane >> 4;
  const int wm = w >> 2, wn = w & 3;
  // XCD-aware swizzle (384 blocks, 384%8==0)
  const int bid = blockIdx.x;
  const int wg = (bid & 7) * 48 + (bid >> 3);
  const int tn = wg % 24, tm = wg / 24;
  const int m0 = tm << 8, n0 = tn << 8;
  const int mat = n0 >> 11;  // 0=Q 1=K 2=V

  f32x4 acc[8][4];
#pragma unroll
  for (int i = 0; i < 8; ++i)
#pragma unroll
    for (int j = 0; j < 4; ++j) {
      f32x4 z = {0.f, 0.f, 0.f, 0.f};
      acc[i][j] = z;
    }

  const int srow8 = lane >> 3;   // 0..7
  const int sseg = lane & 7;

  // stage round j (64 rows) of A or B of K-tile t into buf t&1
  auto stageA = [&](int t, int j) {
    int row = j * 64 + w * 8 + srow8;
    int sg = sseg ^ (row & 7);
    gll16(&A[(size_t)(m0 + row) * DD + t * 64 + sg * 8],
          &smem[t & 1][j * 4096 + w * 512]);
  };
  auto stageB = [&](int t, int j) {
    int row = j * 64 + w * 8 + srow8;
    int sg = sseg ^ (row & 7);
    gll16(&Bt[(size_t)(n0 + row) * DD + t * 64 + sg * 8],
          &smem[t & 1][16384 + j * 4096 + w * 512]);
  };

  // prologue: stage tile 0
#pragma unroll
  for (int j = 0; j < 4; ++j) { stageA(0, j); stageB(0, j); }
  asm volatile("s_waitcnt vmcnt(0)" ::: "memory");
  __builtin_amdgcn_s_barrier();
  __builtin_amdgcn_sched_barrier(0);

  for (int t = 0; t < 32; ++t) {
    const short* Ab = &smem[t & 1][0];
    const short* Bb = &smem[t & 1][16384];
#pragma unroll
    for (int q = 0; q < 4; ++q) {
      const int mq = q >> 1, nq = q & 1;
      // ds-read this quadrant's fragments
      bf16x8 af[2][4], bfv[2][2];
#pragma unroll
      for (int ks = 0; ks < 2; ++ks) {
#pragma unroll
        for (int f = 0; f < 4; ++f) {
          int ra = wm * 128 + mq * 64 + f * 16 + cl;
          af[ks][f] = *reinterpret_cast<const bf16x8*>(
              &Ab[(ra * 64 + ks * 32 + gq * 8) ^ ((ra & 7) << 3)]);
        }
#pragma unroll
        for (int g = 0; g < 2; ++g) {
          int rb = wn * 64 + nq * 32 + g * 16 + cl;
          bfv[ks][g] = *reinterpret_cast<const bf16x8*>(
              &Bb[(rb * 64 + ks * 32 + gq * 8) ^ ((rb & 7) << 3)]);
        }
      }
      // front-loaded staging of tile t+1 into the other buffer
      if (t + 1 < 32) {
        if (q == 0) { stageA(t + 1, 0); stageA(t + 1, 1); stageB(t + 1, 0); stageB(t + 1, 1); }
        else if (q == 1) { stageA(t + 1, 2); stageA(t + 1, 3); stageB(t + 1, 2); stageB(t + 1, 3); }
      }
      __builtin_amdgcn_s_barrier();
      __builtin_amdgcn_s_setprio(1);
#pragma unroll
      for (int ks = 0; ks < 2; ++ks)
#pragma unroll
        for (int f = 0; f < 4; ++f)
#pragma unroll
          for (int g = 0; g < 2; ++g)
            acc[mq * 4 + f][nq * 2 + g] = __builtin_amdgcn_mfma_f32_16x16x32_bf16(
                af[ks][f], bfv[ks][g], acc[mq * 4 + f][nq * 2 + g], 0, 0, 0);
      __builtin_amdgcn_s_setprio(0);
      __builtin_amdgcn_s_barrier();
    }
    // tile boundary: next tile's buffer fully landed for ALL waves
    asm volatile("s_waitcnt vmcnt(0)" ::: "memory");
    __builtin_amdgcn_s_barrier();
    __builtin_amdgcn_sched_barrier(0);
  }

  // ---- epilogue ----
  if (mat < 2) {
    const float qs = (mat == 0) ? 0.127517448f : 1.0f;  // log2e/sqrt(128)
    short* Dst = (mat == 0) ? Qb : Kb;
#pragma unroll
    for (int fm = 0; fm < 8; ++fm)
#pragma unroll
      for (int r = 0; r < 4; ++r) {
        int mrow = m0 + wm * 128 + fm * 16 + gq * 4 + r;
        int s = mrow & (SS - 1);
#pragma unroll
        for (int fn = 0; fn < 4; ++fn) {
          int ncol = n0 + wn * 64 + fn * 16 + cl;
          int c = ncol & 127;
          int i = c >> 1;
          float cv = fc[s * 64 + i], sv = fs[s * 64 + i];
          float v = acc[fm][fn][r];
          float vp = __shfl_xor(v, 1, 64);
          float o = (c & 1) ? (v * cv + vp * sv) : (v * cv - vp * sv);
          Dst[(size_t)mrow * DD + (ncol & (DD - 1))] = f2bf(o * qs);
        }
      }
  } else {
#pragma unroll
    for (int fm = 0; fm < 8; ++fm)
#pragma unroll
      for (int r = 0; r < 4; ++r) {
        int mrow = m0 + wm * 128 + fm * 16 + gq * 4 + r;
#pragma unroll
        for (int fn = 0; fn < 4; ++fn) {
          int ncol = n0 + wn * 64 + fn * 16 + cl;
          Vb[(size_t)mrow * DD + (ncol - 4096)] = f2bf(acc[fm][fn][r]);
        }
      }
  }
}

// ---------------- GEMM: C(M,N) = A(M,K) * Bt(N,K)^T, bf16 in, fp32 out (Wo) ----
__global__ __launch_bounds__(256) void gemm_kernel(
    const short* __restrict__ A, const short* __restrict__ Bt, float* __restrict__ C,
    int Mdim, int Ndim, int Kdim) {
  __shared__ short As[128 * 64];
  __shared__ short Bs[128 * 64];
  int tid = threadIdx.x;
  int lane = tid & 63, w = tid >> 6;
  int cl = lane & 15, gq = lane >> 4;
  int wm = w >> 1, wn = w & 1;
  int m0 = blockIdx.y << 7, n0 = blockIdx.x << 7;
  f32x4 acc[4][4];
#pragma unroll
  for (int i = 0; i < 4; ++i)
#pragma unroll
    for (int j = 0; j < 4; ++j) {
      f32x4 z = {0.f, 0.f, 0.f, 0.f};
      acc[i][j] = z;
    }
  int lrow = lane >> 3;
  int lseg = (lane & 7) ^ lrow;

  for (int k0 = 0; k0 < Kdim; k0 += 64) {
#pragma unroll
    for (int i = 0; i < 4; ++i) {
      int r0 = ((w << 2) + i) << 3;
      gll16(&A[(size_t)(m0 + r0 + lrow) * Kdim + k0 + (lseg << 3)], &As[r0 << 6]);
      gll16(&Bt[(size_t)(n0 + r0 + lrow) * Kdim + k0 + (lseg << 3)], &Bs[r0 << 6]);
    }
    __syncthreads();
#pragma unroll
    for (int ks = 0; ks < 2; ++ks) {
      bf16x8 af[4], bfr[4];
#pragma unroll
      for (int f = 0; f < 4; ++f) {
        int ra = (wm << 6) + (f << 4) + cl;
        af[f] = *reinterpret_cast<const bf16x8*>(
            &As[((ra << 6) + (ks << 5) + (gq << 3)) ^ ((ra & 7) << 3)]);
        int rb = (wn << 6) + (f << 4) + cl;
        bfr[f] = *reinterpret_cast<const bf16x8*>(
            &Bs[((rb << 6) + (ks << 5) + (gq << 3)) ^ ((rb & 7) << 3)]);
      }
#pragma unroll
      for (int fm = 0; fm < 4; ++fm)
#pragma unroll
        for (int fn = 0; fn < 4; ++fn)
          acc[fm][fn] = __builtin_amdgcn_mfma_f32_16x16x32_bf16(
              af[fm], bfr[fn], acc[fm][fn], 0, 0, 0);
    }
    __syncthreads();
  }
#pragma unroll
  for (int fm = 0; fm < 4; ++fm)
#pragma unroll
    for (int r = 0; r < 4; ++r) {
      int mrow = m0 + (wm << 6) + (fm << 4) + (gq << 2) + r;
#pragma unroll
      for (int fn = 0; fn < 4; ++fn) {
        int ncol = n0 + (wn << 6) + (fn << 4) + cl;
        C[(size_t)mrow * Ndim + ncol] = acc[fm][fn][r];
      }
    }
}

// ---------------- flash attention, swapped-QK^T 32x32, T3-min pipelined ----------------
// Logits arrive in base-2 units (Q pre-scaled by (1/sqrt(HD))*log2e) -> exp2f.
__global__ __launch_bounds__(256, 2) void attn_kernel(
    const short* __restrict__ Q, const short* __restrict__ K,
    const short* __restrict__ Vt, short* __restrict__ O) {
  __shared__ short Kl[2][64 * 128];
  __shared__ short Vl[2][128 * 64];
  const int id = blockIdx.x;
  const int qi = 15 - (id >> 5);
  const int bh = id & 31;
  const int b = bh >> 4, h = bh & 15;
  const int tid = threadIdx.x;
  const int lane = tid & 63, w = tid >> 6;
  const int l31 = lane & 31, hi = lane >> 5;
  const int qw = qi * 128 + w * 32;
  const int qg = qw + l31;

  const short* Kbase = K + (size_t)b * SS * DD + h * HDIM;
  const short* Vbase = Vt + (size_t)bh * HDIM * SS;
  int krow[4], kq[4], vd[4], vs[4];
#pragma unroll
  for (int i = 0; i < 4; ++i) {
    int c = w * 4 + i;
    krow[i] = c * 4 + (lane >> 4);
    kq[i] = (lane & 15) ^ (krow[i] & 7);
    vd[i] = c * 8 + (lane >> 3);
    vs[i] = (lane & 7) ^ (vd[i] & 7);
  }

  bf16x8 qf[8];
  const size_t qoff = ((size_t)b * SS + qg) * DD + h * HDIM;
#pragma unroll
  for (int s = 0; s < 8; ++s)
    qf[s] = *reinterpret_cast<const bf16x8*>(&Q[qoff + s * 16 + hi * 8]);

  f32x16 ot[4];
#pragma unroll
  for (int dt = 0; dt < 4; ++dt)
#pragma unroll
    for (int r = 0; r < 16; ++r) ot[dt][r] = 0.f;
  float m_run = -INFINITY, l_run = 0.f;

  const int NT = 2 * qi + 2;

#pragma unroll
  for (int i = 0; i < 4; ++i) {
    gll16(Kbase + (size_t)krow[i] * DD + kq[i] * 8, &Kl[0][(w * 4 + i) * 512]);
    gll16(Vbase + (size_t)vd[i] * SS + vs[i] * 8, &Vl[0][(w * 4 + i) * 512]);
  }
  __syncthreads();

  for (int t = 0; t < NT; ++t) {
    const int cur = t & 1;
    if (t + 1 < NT) {
      const int nt64 = (t + 1) * 64;
#pragma unroll
      for (int i = 0; i < 4; ++i) {
        gll16(Kbase + (size_t)(nt64 + krow[i]) * DD + kq[i] * 8,
              &Kl[cur ^ 1][(w * 4 + i) * 512]);
        gll16(Vbase + (size_t)vd[i] * SS + nt64 + vs[i] * 8,
              &Vl[cur ^ 1][(w * 4 + i) * 512]);
      }
    }

    if (t * 64 <= qw + 31) {
      const short* Kc = Kl[cur];
      const short* Vc = Vl[cur];
      f32x16 st0, st1;
#pragma unroll
      for (int r = 0; r < 16; ++r) { st0[r] = 0.f; st1[r] = 0.f; }
      __builtin_amdgcn_s_setprio(1);
#pragma unroll
      for (int s = 0; s < 8; ++s) {
        const int cs = (s * 2 + hi);
        bf16x8 kf0 = *reinterpret_cast<const bf16x8*>(
            &Kc[l31 * 128 + ((cs ^ (l31 & 7)) << 3)]);
        st0 = __builtin_amdgcn_mfma_f32_32x32x16_bf16(kf0, qf[s], st0, 0, 0, 0);
        bf16x8 kf1 = *reinterpret_cast<const bf16x8*>(
            &Kc[(32 + l31) * 128 + ((cs ^ (l31 & 7)) << 3)]);
        st1 = __builtin_amdgcn_mfma_f32_32x32x16_bf16(kf1, qf[s], st1, 0, 0, 0);
      }
      __builtin_amdgcn_s_setprio(0);
      if (t * 64 + 63 > qw) {
#pragma unroll
        for (int r = 0; r < 16; ++r) {
          int dl = (r & 3) + 8 * (r >> 2) + 4 * hi;
          if (t * 64 + dl > qg) st0[r] = -1e30f;
          if (t * 64 + 32 + dl > qg) st1[r] = -1e30f;
        }
      }
      // ---- online softmax (base-2), tree reductions, defer-max ----
      float mx[16];
#pragma unroll
      for (int r = 0; r < 16; ++r) mx[r] = fmaxf(st0[r], st1[r]);
#pragma unroll
      for (int off = 8; off >= 1; off >>= 1)
#pragma unroll
        for (int r = 0; r < 8; ++r)
          if (r < off) mx[r] = fmaxf(mx[r], mx[r + off]);
      float pm = mx[0];
      {
        auto sw = __builtin_amdgcn_permlane32_swap(asi(pm), asi(pm), false, false);
        pm = fmaxf(asf(sw[0]), asf(sw[1]));
      }
      if (!__all(pm <= m_run + 11.5f)) {
        float mn = fmaxf(m_run, pm);
        float al = exp2f(m_run - mn);
        m_run = mn;
        l_run *= al;
#pragma unroll
        for (int dt = 0; dt < 4; ++dt)
#pragma unroll
          for (int r = 0; r < 16; ++r) ot[dt][r] *= al;
      }
#pragma unroll
      for (int r = 0; r < 16; ++r) st0[r] = exp2f(st0[r] - m_run);
#pragma unroll
      for (int r = 0; r < 16; ++r) st1[r] = exp2f(st1[r] - m_run);
      float sm[16];
#pragma unroll
      for (int r = 0; r < 16; ++r) sm[r] = st0[r] + st1[r];
#pragma unroll
      for (int off = 8; off >= 1; off >>= 1)
#pragma unroll
        for (int r = 0; r < 8; ++r)
          if (r < off) sm[r] += sm[r + off];
      float ps = sm[0];
      {
        auto sw = __builtin_amdgcn_permlane32_swap(asi(ps), asi(ps), false, false);
        ps = asf(sw[0]) + asf(sw[1]);
      }
      l_run += ps;

      // ---- pack P -> bf16 B-frags via cvt_pk + permlane32_swap (T12) ----
      bf16x8 pf[4];
#pragma unroll
      for (int s = 0; s < 4; ++s) {
        float e0, e1, e2, e3, e4, e5, e6, e7;
        if (s < 2) {
          e0 = st0[8 * s + 0]; e1 = st0[8 * s + 1]; e2 = st0[8 * s + 2]; e3 = st0[8 * s + 3];
          e4 = st0[8 * s + 4]; e5 = st0[8 * s + 5]; e6 = st0[8 * s + 6]; e7 = st0[8 * s + 7];
        } else {
          e0 = st1[8 * (s - 2) + 0]; e1 = st1[8 * (s - 2) + 1]; e2 = st1[8 * (s - 2) + 2]; e3 = st1[8 * (s - 2) + 3];
          e4 = st1[8 * (s - 2) + 4]; e5 = st1[8 * (s - 2) + 5]; e6 = st1[8 * (s - 2) + 6]; e7 = st1[8 * (s - 2) + 7];
        }
        unsigned a0 = cvtpk_bf16(e0, e1);
        unsigned a1 = cvtpk_bf16(e2, e3);
        unsigned b0 = cvtpk_bf16(e4, e5);
        unsigned b1 = cvtpk_bf16(e6, e7);
        auto r0 = __builtin_amdgcn_permlane32_swap((int)a0, (int)b0, false, false);
        auto r1 = __builtin_amdgcn_permlane32_swap((int)a1, (int)b1, false, false);
        union { int u[4]; bf16x8 v; } pk;
        pk.u[0] = r0[0]; pk.u[1] = r1[0]; pk.u[2] = r0[1]; pk.u[3] = r1[1];
        pf[s] = pk.v;
      }

      __builtin_amdgcn_s_setprio(1);
#pragma unroll
      for (int dt = 0; dt < 4; ++dt) {
        const int vr = dt * 32 + l31;
#pragma unroll
        for (int s = 0; s < 4; ++s) {
          bf16x8 vf = *reinterpret_cast<const bf16x8*>(
              &Vc[vr * 64 + (((s * 2 + hi) ^ (vr & 7)) << 3)]);
          ot[dt] = __builtin_amdgcn_mfma_f32_32x32x16_bf16(vf, pf[s], ot[dt], 0, 0, 0);
        }
      }
      __builtin_amdgcn_s_setprio(0);
    }
    __syncthreads();
  }

  float inv = 1.0f / l_run;
  const size_t orow = ((size_t)b * SS + qg) * DD + h * HDIM;
#pragma unroll
  for (int dt = 0; dt < 4; ++dt)
#pragma unroll
    for (int g = 0; g < 4; ++g) {
      bf16x4 v;
#pragma unroll
      for (int k = 0; k < 4; ++k) v[k] = f2bf(ot[dt][4 * g + k] * inv);
      *reinterpret_cast<bf16x4*>(&O[orow + dt * 32 + 8 * g + 4 * hi]) = v;
    }
}

extern "C" void kernel_launch(void* const* d_in, const int* in_sizes, int n_in,
                              void* d_out, int out_size, void* d_ws, size_t ws_size,
                              hipStream_t stream) {
  const float* x = (const float*)d_in[0];
  const float* Wq = (const float*)d_in[1];
  const float* Wk = (const float*)d_in[2];
  const float* Wv = (const float*)d_in[3];
  const float* Wo = (const float*)d_in[4];
  const float* fc = (const float*)d_in[5];
  const float* fs = (const float*)d_in[6];
  float* out = (float*)d_out;
  char* ws = (char*)d_ws;

  short* xb     = (short*)(ws + 0);                      // 16MB; reused as attn_out
  short* WqkvT  = (short*)(ws + (size_t)16 * 1048576);   // 24MB; reused as VtB
  short* WoT    = (short*)(ws + (size_t)40 * 1048576);   // 8MB
  short* Qb     = (short*)(ws + (size_t)48 * 1048576);   // 16MB
  short* Kb     = (short*)(ws + (size_t)64 * 1048576);   // 16MB
  short* Vb     = (short*)(ws + (size_t)80 * 1048576);   // 16MB (plain V)
  short* VtB    = WqkvT;                                 // alias (dead after qkv gemm)

  cast_bf16_kernel<<<8192, 256, 0, stream>>>(x, xb, 2097152);
  dim3 tg(32, 32);
  transpose_cast_kernel<<<tg, 256, 0, stream>>>(Wq, WqkvT);
  transpose_cast_kernel<<<tg, 256, 0, stream>>>(Wk, WqkvT + (size_t)2048 * 2048);
  transpose_cast_kernel<<<tg, 256, 0, stream>>>(Wv, WqkvT + (size_t)4096 * 2048);
  transpose_cast_kernel<<<tg, 256, 0, stream>>>(Wo, WoT);

  qkv_gemm8_kernel<<<384, 512, 0, stream>>>(xb, WqkvT, Qb, Kb, Vb, fc, fs);

  transpose_v_kernel<<<dim3(32, 2, 32), 256, 0, stream>>>(Vb, VtB);

  attn_kernel<<<512, 256, 0, stream>>>(Qb, Kb, VtB, xb);  // attn_out = xb

  gemm_kernel<<<dim3(16, 32), 256, 0, stream>>>(xb, WoT, out, MM, DD, DD);
}

// Round 6
// 281.943 us; speedup vs baseline: 1.0435x; 1.0435x over previous
//
#include <hip/hip_runtime.h>
#include <cstdint>

#define BB 2
#define SS 2048
#define DD 2048
#define HH 16
#define HDIM 128
#define MM (BB * SS)  // 4096

typedef __attribute__((ext_vector_type(8))) short bf16x8;
typedef __attribute__((ext_vector_type(4))) short bf16x4;
typedef __attribute__((ext_vector_type(4))) float f32x4;
typedef __attribute__((ext_vector_type(16))) float f32x16;

__device__ inline short f2bf(float f) {
  union { float f; unsigned u; } v; v.f = f;
  unsigned r = v.u + 0x7FFFu + ((v.u >> 16) & 1u);
  return (short)(r >> 16);
}
__device__ inline float bf2f(short s) {
  union { float f; unsigned u; } v;
  v.u = ((unsigned)(unsigned short)s) << 16;
  return v.f;
}
__device__ inline float asf(int u) { union { int i; float f; } v; v.i = u; return v.f; }
__device__ inline int asi(float f) { union { float f; int i; } v; v.f = f; return v.i; }

__device__ inline unsigned cvtpk_bf16(float lo, float hi) {
  unsigned r;
  asm("v_cvt_pk_bf16_f32 %0, %1, %2" : "=v"(r) : "v"(lo), "v"(hi));
  return r;
}

__device__ inline void gll16(const void* g, void* l) {
  __builtin_amdgcn_global_load_lds(
      (const __attribute__((address_space(1))) void*)g,
      (__attribute__((address_space(3))) void*)l, 16, 0, 0);
}

// ---------------- cast fp32 -> bf16 ----------------
__global__ __launch_bounds__(256) void cast_bf16_kernel(
    const float* __restrict__ x, short* __restrict__ y, int n4) {
  int i = blockIdx.x * 256 + threadIdx.x;
  if (i >= n4) return;
  float4 v = reinterpret_cast<const float4*>(x)[i];
  bf16x4 o;
  o[0] = f2bf(v.x); o[1] = f2bf(v.y); o[2] = f2bf(v.z); o[3] = f2bf(v.w);
  reinterpret_cast<bf16x4*>(y)[i] = o;
}

// ---------------- all 4 weight transposes in ONE launch (z = 0..3) ----------------
__global__ __launch_bounds__(256) void transpose4_kernel(
    const float* __restrict__ Wq, const float* __restrict__ Wk,
    const float* __restrict__ Wv, const float* __restrict__ Wo,
    short* __restrict__ WqkvT, short* __restrict__ WoT) {
  __shared__ short tile[64][65];
  int z = blockIdx.z;
  const float* W = (z == 0) ? Wq : (z == 1) ? Wk : (z == 2) ? Wv : Wo;
  short* Wt = (z < 3) ? (WqkvT + (size_t)z * DD * DD) : WoT;
  int c = threadIdx.x & 63, r4 = threadIdx.x >> 6;
  int n0 = blockIdx.x << 6, k0 = blockIdx.y << 6;
#pragma unroll
  for (int p = 0; p < 16; ++p) {
    int r = (p << 2) + r4;
    tile[c][r] = f2bf(W[(size_t)(k0 + r) * DD + n0 + c]);
  }
  __syncthreads();
#pragma unroll
  for (int p = 0; p < 16; ++p) {
    int r = (p << 2) + r4;
    Wt[(size_t)(n0 + r) * DD + k0 + c] = tile[r][c];
  }
}

// ---------------- transpose V (B,S,D) bf16 head-slices -> Vt (B*H, 128, S) ----------------
__global__ __launch_bounds__(256) void transpose_v_kernel(
    const short* __restrict__ V, short* __restrict__ Vt) {
  __shared__ short tile[64][65];
  int c = threadIdx.x & 63, r4 = threadIdx.x >> 6;
  int s0 = blockIdx.x << 6, d0 = blockIdx.y << 6;
  int bh = blockIdx.z;
  int b = bh >> 4, h = bh & 15;
#pragma unroll
  for (int p = 0; p < 16; ++p) {
    int r = (p << 2) + r4;  // s-local
    tile[c][r] = V[(size_t)(b * SS + s0 + r) * DD + h * HDIM + d0 + c];
  }
  __syncthreads();
#pragma unroll
  for (int p = 0; p < 16; ++p) {
    int r = (p << 2) + r4;  // d-local
    Vt[((size_t)bh * HDIM + d0 + r) * SS + s0 + c] = tile[r][c];
  }
}

// ---------------- fat-phase 256xBN GEMM, counted-vmcnt pipeline ----------------
// C(M=4096, N) = A(4096,2048) * Bt(N,2048)^T, 512 thr = 8 waves (4M x 2N).
// BK=64 split into 2 k-half phases. LDS per buffer: A[2][256][32] + B[2][BN][32]
// shorts (contiguous halves -> gll-compatible), 2-bit XOR seg swizzle (2-way
// conflicts = free). Staging sets: p0 = A-half0 (2 loads) + B-full (LB);
// p1 = A-half1 (2). Steady state: vmcnt(2+LB) mid-tile, vmcnt(2) at boundary,
// never 0 in the loop (T4). 2 barriers per K-tile.
// MODE 0: fused QKV epilogue (per-column: RoPE->Qb/Kb, plain->Vb).
// MODE 1: fp32 store to Cf (Wo projection).
template <int BN, int MODE>
__global__ __launch_bounds__(512) void gemm8_kernel(
    const short* __restrict__ A, const short* __restrict__ Bt,
    short* __restrict__ Qb, short* __restrict__ Kb, short* __restrict__ Vb,
    float* __restrict__ Cf,
    const float* __restrict__ fc, const float* __restrict__ fs) {
  constexpr int FN = BN / 32;       // frags per wave in N (6 or 4)
  constexpr int LB = BN / 64;       // B gll loads per thread (3 or 2)
  constexpr int BH = BN * 32;       // shorts per B k-half
  __shared__ short smem[2][16384 + BN * 64];

  const int tid = threadIdx.x;
  const int lane = tid & 63, w = tid >> 6;
  const int cl = lane & 15, gq = lane >> 4;
  const int wm = w >> 1, wn = w & 1;   // 4M x 2N wave grid

  // XCD-chunked tile map: each XCD owns a (BN==192 ? 4 : 2)-wide tn strip.
  const int bid = blockIdx.x;
  const int xcd = bid & 7, local = bid >> 3;
  constexpr int TNX = (BN == 192) ? 4 : 2;
  const int tm = local & 15, tn = xcd * TNX + (local >> 4);
  const int m0 = tm << 8, n0 = tn * BN;

  f32x4 acc[4][FN];
#pragma unroll
  for (int i = 0; i < 4; ++i)
#pragma unroll
    for (int j = 0; j < FN; ++j) {
      f32x4 z = {0.f, 0.f, 0.f, 0.f};
      acc[i][j] = z;
    }

  // stage A load l (l=0,1: k-half0 rows 0..255; l=2,3: k-half1)
  auto stageA = [&](int t, int l, short* buf) {
    int D = l * 8192 + tid * 16;              // dest byte in A region
    int half = D >> 14;
    int row = (D >> 6) & 255;
    int p2 = (D >> 4) & 3;
    int col = t * 64 + half * 32 + ((p2 ^ (row & 3)) << 3);
    gll16(&A[(size_t)(m0 + row) * DD + col], (char*)buf + D);
  };
  // stage B load l (covers both halves contiguously)
  auto stageB = [&](int t, int l, short* buf) {
    int D = l * 8192 + tid * 16;              // dest byte in B region
    int half = (D >= BN * 64) ? 1 : 0;
    int row = (D - half * BN * 64) >> 6;
    int p2 = (D >> 4) & 3;
    int col = t * 64 + half * 32 + ((p2 ^ (row & 3)) << 3);
    gll16(&Bt[(size_t)(n0 + row) * DD + col], (char*)buf + 32768 + D);
  };

  auto compute = [&](const short* base, int ks) {
    const short* Ab = base;
    const short* Bb = base + 16384;
    bf16x8 af[4], bfv[FN];
#pragma unroll
    for (int fm = 0; fm < 4; ++fm) {
      int ra = wm * 64 + fm * 16 + cl;
      af[fm] = *reinterpret_cast<const bf16x8*>(
          &Ab[ks * 8192 + ra * 32 + ((gq ^ (ra & 3)) << 3)]);
    }
#pragma unroll
    for (int fn = 0; fn < FN; ++fn) {
      int rb = wn * (BN / 2) + fn * 16 + cl;
      bfv[fn] = *reinterpret_cast<const bf16x8*>(
          &Bb[ks * BH + rb * 32 + ((gq ^ (rb & 3)) << 3)]);
    }
    __builtin_amdgcn_s_setprio(1);
#pragma unroll
    for (int fm = 0; fm < 4; ++fm)
#pragma unroll
      for (int fn = 0; fn < FN; ++fn)
        acc[fm][fn] = __builtin_amdgcn_mfma_f32_16x16x32_bf16(
            af[fm], bfv[fn], acc[fm][fn], 0, 0, 0);
    __builtin_amdgcn_s_setprio(0);
  };

  // prologue: tile 0 fully staged (p0set then p1set; one-time drain of p0set)
  stageA(0, 0, smem[0]); stageA(0, 1, smem[0]);
#pragma unroll
  for (int l = 0; l < LB; ++l) stageB(0, l, smem[0]);
  stageA(0, 2, smem[0]); stageA(0, 3, smem[0]);
  asm volatile("s_waitcnt vmcnt(2)" ::: "memory");
  __builtin_amdgcn_s_barrier();

  for (int t = 0; t < 31; ++t) {
    short* cur = smem[t & 1];
    short* nxt = smem[(t + 1) & 1];
    // phase 0 (ks=0): issue next tile's p0set, compute, counted wait
    stageA(t + 1, 0, nxt); stageA(t + 1, 1, nxt);
#pragma unroll
    for (int l = 0; l < LB; ++l) stageB(t + 1, l, nxt);
    compute(cur, 0);
    if constexpr (BN == 192)
      asm volatile("s_waitcnt vmcnt(5)" ::: "memory");  // leaves (t+1).p0set
    else
      asm volatile("s_waitcnt vmcnt(4)" ::: "memory");
    __builtin_amdgcn_s_barrier();
    // phase 1 (ks=1): issue next tile's p1set, compute, counted wait
    stageA(t + 1, 2, nxt); stageA(t + 1, 3, nxt);
    compute(cur, 1);
    asm volatile("s_waitcnt vmcnt(2)" ::: "memory");    // leaves (t+1).p1set
    __builtin_amdgcn_s_barrier();
  }
  // peeled last tile (t=31): drain remaining p1set before its phase 1
  compute(smem[1], 0);
  asm volatile("s_waitcnt vmcnt(0)" ::: "memory");
  __builtin_amdgcn_s_barrier();
  compute(smem[1], 1);

  // ---- epilogue ----
  if constexpr (MODE == 0) {
#pragma unroll
    for (int fm = 0; fm < 4; ++fm)
#pragma unroll
      for (int r = 0; r < 4; ++r) {
        int mrow = m0 + wm * 64 + fm * 16 + gq * 4 + r;
        int s = mrow & (SS - 1);
#pragma unroll
        for (int fn = 0; fn < FN; ++fn) {
          int ncol = n0 + wn * (BN / 2) + fn * 16 + cl;
          float v = acc[fm][fn][r];
          float vp = __shfl_xor(v, 1, 64);
          if (ncol < 4096) {
            int c = ncol & 127;
            int i = c >> 1;
            float cv = fc[s * 64 + i], sv = fs[s * 64 + i];
            float o = (c & 1) ? (v * cv + vp * sv) : (v * cv - vp * sv);
            float qs = (ncol < 2048) ? 0.127517448f : 1.0f;  // log2e/sqrt(128)
            short* Dp = (ncol < 2048) ? Qb : Kb;
            Dp[(size_t)mrow * DD + (ncol & (DD - 1))] = f2bf(o * qs);
          } else {
            Vb[(size_t)mrow * DD + (ncol - 4096)] = f2bf(v);
          }
        }
      }
  } else {
#pragma unroll
    for (int fm = 0; fm < 4; ++fm)
#pragma unroll
      for (int r = 0; r < 4; ++r) {
        int mrow = m0 + wm * 64 + fm * 16 + gq * 4 + r;
#pragma unroll
        for (int fn = 0; fn < FN; ++fn) {
          int ncol = n0 + wn * (BN / 2) + fn * 16 + cl;
          Cf[(size_t)mrow * DD + ncol] = acc[fm][fn][r];
        }
      }
  }
}

// ---------------- flash attention, swapped-QK^T 32x32, T3-min pipelined ----------------
// Logits arrive in base-2 units (Q pre-scaled by (1/sqrt(HD))*log2e) -> exp2f.
__global__ __launch_bounds__(256, 2) void attn_kernel(
    const short* __restrict__ Q, const short* __restrict__ K,
    const short* __restrict__ Vt, short* __restrict__ O) {
  __shared__ short Kl[2][64 * 128];
  __shared__ short Vl[2][128 * 64];
  const int id = blockIdx.x;
  const int qi = 15 - (id >> 5);
  const int bh = id & 31;
  const int b = bh >> 4, h = bh & 15;
  const int tid = threadIdx.x;
  const int lane = tid & 63, w = tid >> 6;
  const int l31 = lane & 31, hi = lane >> 5;
  const int qw = qi * 128 + w * 32;
  const int qg = qw + l31;

  const short* Kbase = K + (size_t)b * SS * DD + h * HDIM;
  const short* Vbase = Vt + (size_t)bh * HDIM * SS;
  int krow[4], kq[4], vd[4], vs[4];
#pragma unroll
  for (int i = 0; i < 4; ++i) {
    int c = w * 4 + i;
    krow[i] = c * 4 + (lane >> 4);
    kq[i] = (lane & 15) ^ (krow[i] & 7);
    vd[i] = c * 8 + (lane >> 3);
    vs[i] = (lane & 7) ^ (vd[i] & 7);
  }

  bf16x8 qf[8];
  const size_t qoff = ((size_t)b * SS + qg) * DD + h * HDIM;
#pragma unroll
  for (int s = 0; s < 8; ++s)
    qf[s] = *reinterpret_cast<const bf16x8*>(&Q[qoff + s * 16 + hi * 8]);

  f32x16 ot[4];
#pragma unroll
  for (int dt = 0; dt < 4; ++dt)
#pragma unroll
    for (int r = 0; r < 16; ++r) ot[dt][r] = 0.f;
  float m_run = -INFINITY, l_run = 0.f;

  const int NT = 2 * qi + 2;

#pragma unroll
  for (int i = 0; i < 4; ++i) {
    gll16(Kbase + (size_t)krow[i] * DD + kq[i] * 8, &Kl[0][(w * 4 + i) * 512]);
    gll16(Vbase + (size_t)vd[i] * SS + vs[i] * 8, &Vl[0][(w * 4 + i) * 512]);
  }
  __syncthreads();

  for (int t = 0; t < NT; ++t) {
    const int cur = t & 1;
    if (t + 1 < NT) {
      const int nt64 = (t + 1) * 64;
#pragma unroll
      for (int i = 0; i < 4; ++i) {
        gll16(Kbase + (size_t)(nt64 + krow[i]) * DD + kq[i] * 8,
              &Kl[cur ^ 1][(w * 4 + i) * 512]);
        gll16(Vbase + (size_t)vd[i] * SS + nt64 + vs[i] * 8,
              &Vl[cur ^ 1][(w * 4 + i) * 512]);
      }
    }

    if (t * 64 <= qw + 31) {
      const short* Kc = Kl[cur];
      const short* Vc = Vl[cur];
      f32x16 st0, st1;
#pragma unroll
      for (int r = 0; r < 16; ++r) { st0[r] = 0.f; st1[r] = 0.f; }
      __builtin_amdgcn_s_setprio(1);
#pragma unroll
      for (int s = 0; s < 8; ++s) {
        const int cs = (s * 2 + hi);
        bf16x8 kf0 = *reinterpret_cast<const bf16x8*>(
            &Kc[l31 * 128 + ((cs ^ (l31 & 7)) << 3)]);
        st0 = __builtin_amdgcn_mfma_f32_32x32x16_bf16(kf0, qf[s], st0, 0, 0, 0);
        bf16x8 kf1 = *reinterpret_cast<const bf16x8*>(
            &Kc[(32 + l31) * 128 + ((cs ^ (l31 & 7)) << 3)]);
        st1 = __builtin_amdgcn_mfma_f32_32x32x16_bf16(kf1, qf[s], st1, 0, 0, 0);
      }
      __builtin_amdgcn_s_setprio(0);
      if (t * 64 + 63 > qw) {
#pragma unroll
        for (int r = 0; r < 16; ++r) {
          int dl = (r & 3) + 8 * (r >> 2) + 4 * hi;
          if (t * 64 + dl > qg) st0[r] = -1e30f;
          if (t * 64 + 32 + dl > qg) st1[r] = -1e30f;
        }
      }
      // ---- online softmax (base-2), tree reductions, defer-max ----
      float mx[16];
#pragma unroll
      for (int r = 0; r < 16; ++r) mx[r] = fmaxf(st0[r], st1[r]);
#pragma unroll
      for (int off = 8; off >= 1; off >>= 1)
#pragma unroll
        for (int r = 0; r < 8; ++r)
          if (r < off) mx[r] = fmaxf(mx[r], mx[r + off]);
      float pm = mx[0];
      {
        auto sw = __builtin_amdgcn_permlane32_swap(asi(pm), asi(pm), false, false);
        pm = fmaxf(asf(sw[0]), asf(sw[1]));
      }
      if (!__all(pm <= m_run + 11.5f)) {
        float mn = fmaxf(m_run, pm);
        float al = exp2f(m_run - mn);
        m_run = mn;
        l_run *= al;
#pragma unroll
        for (int dt = 0; dt < 4; ++dt)
#pragma unroll
          for (int r = 0; r < 16; ++r) ot[dt][r] *= al;
      }
#pragma unroll
      for (int r = 0; r < 16; ++r) st0[r] = exp2f(st0[r] - m_run);
#pragma unroll
      for (int r = 0; r < 16; ++r) st1[r] = exp2f(st1[r] - m_run);
      float sm[16];
#pragma unroll
      for (int r = 0; r < 16; ++r) sm[r] = st0[r] + st1[r];
#pragma unroll
      for (int off = 8; off >= 1; off >>= 1)
#pragma unroll
        for (int r = 0; r < 8; ++r)
          if (r < off) sm[r] += sm[r + off];
      float ps = sm[0];
      {
        auto sw = __builtin_amdgcn_permlane32_swap(asi(ps), asi(ps), false, false);
        ps = asf(sw[0]) + asf(sw[1]);
      }
      l_run += ps;

      // ---- pack P -> bf16 B-frags via cvt_pk + permlane32_swap (T12) ----
      bf16x8 pf[4];
#pragma unroll
      for (int s = 0; s < 4; ++s) {
        float e0, e1, e2, e3, e4, e5, e6, e7;
        if (s < 2) {
          e0 = st0[8 * s + 0]; e1 = st0[8 * s + 1]; e2 = st0[8 * s + 2]; e3 = st0[8 * s + 3];
          e4 = st0[8 * s + 4]; e5 = st0[8 * s + 5]; e6 = st0[8 * s + 6]; e7 = st0[8 * s + 7];
        } else {
          e0 = st1[8 * (s - 2) + 0]; e1 = st1[8 * (s - 2) + 1]; e2 = st1[8 * (s - 2) + 2]; e3 = st1[8 * (s - 2) + 3];
          e4 = st1[8 * (s - 2) + 4]; e5 = st1[8 * (s - 2) + 5]; e6 = st1[8 * (s - 2) + 6]; e7 = st1[8 * (s - 2) + 7];
        }
        unsigned a0 = cvtpk_bf16(e0, e1);
        unsigned a1 = cvtpk_bf16(e2, e3);
        unsigned b0 = cvtpk_bf16(e4, e5);
        unsigned b1 = cvtpk_bf16(e6, e7);
        auto r0 = __builtin_amdgcn_permlane32_swap((int)a0, (int)b0, false, false);
        auto r1 = __builtin_amdgcn_permlane32_swap((int)a1, (int)b1, false, false);
        union { int u[4]; bf16x8 v; } pk;
        pk.u[0] = r0[0]; pk.u[1] = r1[0]; pk.u[2] = r0[1]; pk.u[3] = r1[1];
        pf[s] = pk.v;
      }

      __builtin_amdgcn_s_setprio(1);
#pragma unroll
      for (int dt = 0; dt < 4; ++dt) {
        const int vr = dt * 32 + l31;
#pragma unroll
        for (int s = 0; s < 4; ++s) {
          bf16x8 vf = *reinterpret_cast<const bf16x8*>(
              &Vc[vr * 64 + (((s * 2 + hi) ^ (vr & 7)) << 3)]);
          ot[dt] = __builtin_amdgcn_mfma_f32_32x32x16_bf16(vf, pf[s], ot[dt], 0, 0, 0);
        }
      }
      __builtin_amdgcn_s_setprio(0);
    }
    __syncthreads();
  }

  float inv = 1.0f / l_run;
  const size_t orow = ((size_t)b * SS + qg) * DD + h * HDIM;
#pragma unroll
  for (int dt = 0; dt < 4; ++dt)
#pragma unroll
    for (int g = 0; g < 4; ++g) {
      bf16x4 v;
#pragma unroll
      for (int k = 0; k < 4; ++k) v[k] = f2bf(ot[dt][4 * g + k] * inv);
      *reinterpret_cast<bf16x4*>(&O[orow + dt * 32 + 8 * g + 4 * hi]) = v;
    }
}

extern "C" void kernel_launch(void* const* d_in, const int* in_sizes, int n_in,
                              void* d_out, int out_size, void* d_ws, size_t ws_size,
                              hipStream_t stream) {
  const float* x = (const float*)d_in[0];
  const float* Wq = (const float*)d_in[1];
  const float* Wk = (const float*)d_in[2];
  const float* Wv = (const float*)d_in[3];
  const float* Wo = (const float*)d_in[4];
  const float* fc = (const float*)d_in[5];
  const float* fs = (const float*)d_in[6];
  float* out = (float*)d_out;
  char* ws = (char*)d_ws;

  short* xb     = (short*)(ws + 0);                      // 16MB; reused as attn_out
  short* WqkvT  = (short*)(ws + (size_t)16 * 1048576);   // 24MB; reused as VtB
  short* WoT    = (short*)(ws + (size_t)40 * 1048576);   // 8MB
  short* Qb     = (short*)(ws + (size_t)48 * 1048576);   // 16MB
  short* Kb     = (short*)(ws + (size_t)64 * 1048576);   // 16MB
  short* Vb     = (short*)(ws + (size_t)80 * 1048576);   // 16MB (plain V)
  short* VtB    = WqkvT;                                 // alias (dead after qkv gemm)

  cast_bf16_kernel<<<8192, 256, 0, stream>>>(x, xb, 2097152);
  transpose4_kernel<<<dim3(32, 32, 4), 256, 0, stream>>>(Wq, Wk, Wv, Wo, WqkvT, WoT);

  gemm8_kernel<192, 0><<<512, 512, 0, stream>>>(
      xb, WqkvT, Qb, Kb, Vb, nullptr, fc, fs);

  transpose_v_kernel<<<dim3(32, 2, 32), 256, 0, stream>>>(Vb, VtB);

  attn_kernel<<<512, 256, 0, stream>>>(Qb, Kb, VtB, xb);  // attn_out = xb

  gemm8_kernel<128, 1><<<256, 512, 0, stream>>>(
      xb, WoT, nullptr, nullptr, nullptr, out, nullptr, nullptr);
}